// Round 2
// baseline (69.118 us; speedup 1.0000x reference)
//
#include <hip/hip_runtime.h>
#include <hip/hip_cooperative_groups.h>
#include <math.h>

namespace cg = cooperative_groups;

#define S_LEN 2048
#define B_SZ  256
#define I_SZ  128
#define GRID  256
#define BLK   256

// exact identity: tanh(x) = 1 - 2/(1 + e^{2x}); saturates correctly at +/-inf
__device__ __forceinline__ float fast_tanh(float x) {
    float e = __expf(2.0f * x);                       // v_exp_f32
    return 1.0f - 2.0f * __builtin_amdgcn_rcpf(e + 1.0f);
}

// One cooperative kernel, three phases:
//  phase 0 (per-thread, O(K)): truncation window from actual recurrent weights.
//    Starting (h1,h2)=(0,0) at t0=S-K gives |dh2_last| <= (1+K)*m^K (tanh
//    1-Lipschitz, |true h| <= 1); sigmoid Lipschitz 1/4 => out err <= (1+K)m^K/4.
//    Require (1+K)m^K <= 4e-3 => out err <= 1e-3 (threshold 8.5e-3).
//  phase 1: xp[s*B+b] = dot(x[s,b,:], W_ih0) + bias for s >= t0.
//    One wave = 2 vectors/iter; lane loads one float4 (64*16B = 1KiB coalesced),
//    5-step shfl_xor reduce within each 32-lane half.
//  phase 2 (block 0 after grid sync): 256-lane sequential scan + sigmoid.
__global__ __launch_bounds__(BLK) void fused_rnn(
    const float* __restrict__ x,
    const float* __restrict__ W_ih0,
    const float* __restrict__ w_hh0,
    const float* __restrict__ b_ih0,
    const float* __restrict__ b_hh0,
    const float* __restrict__ w_ih1,
    const float* __restrict__ w_hh1,
    const float* __restrict__ b_ih1,
    const float* __restrict__ b_hh1,
    float* __restrict__ xp,
    float* __restrict__ out)
{
    // ---- phase 0: window ----
    const float m = fmaxf(fabsf(w_hh0[0]), fabsf(w_hh1[0]));
    int K = S_LEN;
    float p = 1.0f;
    for (int k = 1; k < S_LEN; ++k) {
        p *= m;
        if (p * (1.0f + (float)k) <= 4.0e-3f) { K = k; break; }
    }
    const int t0 = S_LEN - K;

    // ---- phase 1: matvec for rows >= t0 ----
    {
        const int lane = threadIdx.x & 63;
        const int half = lane >> 5;
        const int l    = lane & 31;
        const int wave  = (blockIdx.x * BLK + threadIdx.x) >> 6;
        const int nwave = (GRID * BLK) >> 6;

        const float4 w4  = ((const float4*)W_ih0)[l];
        const float bias = b_ih0[0] + b_hh0[0];

        const int P         = (S_LEN * B_SZ) / 2;
        const int startPair = t0 * (B_SZ / 2);

        for (int pr = startPair + wave; pr < P; pr += nwave) {
            const int v = 2 * pr + half;               // vector index = s*B + b
            float4 a = ((const float4*)x)[v * (I_SZ / 4) + l];
            float s = a.x * w4.x + a.y * w4.y + a.z * w4.z + a.w * w4.w;
            s += __shfl_xor(s, 1);
            s += __shfl_xor(s, 2);
            s += __shfl_xor(s, 4);
            s += __shfl_xor(s, 8);
            s += __shfl_xor(s, 16);
            if (l == 0) xp[v] = s + bias;
        }
    }

    __threadfence();               // device-scope release before cross-XCD read
    cg::this_grid().sync();

    // ---- phase 2: scan (block 0 only) ----
    if (blockIdx.x != 0) return;
    {
        const int b  = threadIdx.x;
        const float w0 = w_hh0[0];
        const float c  = w_ih1[0];
        const float d  = w_hh1[0];
        const float b1 = b_ih1[0] + b_hh1[0];

        float h1 = 0.0f, h2 = 0.0f;
        float nxt = xp[t0 * B_SZ + b];
        for (int t = t0; t < S_LEN; ++t) {
            float cur = nxt;
            if (t + 1 < S_LEN) nxt = xp[(t + 1) * B_SZ + b];
            h1 = fast_tanh(fmaf(w0, h1, cur));
            h2 = fast_tanh(fmaf(d, h2, fmaf(c, h1, b1)));
        }
        out[b] = __builtin_amdgcn_rcpf(1.0f + __expf(-h2));
    }
}

extern "C" void kernel_launch(void* const* d_in, const int* in_sizes, int n_in,
                              void* d_out, int out_size, void* d_ws, size_t ws_size,
                              hipStream_t stream) {
    const float* x     = (const float*)d_in[0];
    const float* W_ih0 = (const float*)d_in[1];
    const float* W_hh0 = (const float*)d_in[2];
    const float* b_ih0 = (const float*)d_in[3];
    const float* b_hh0 = (const float*)d_in[4];
    const float* W_ih1 = (const float*)d_in[5];
    const float* W_hh1 = (const float*)d_in[6];
    const float* b_ih1 = (const float*)d_in[7];
    const float* b_hh1 = (const float*)d_in[8];
    float* out = (float*)d_out;
    float* xp  = (float*)d_ws;                 // S*B floats = 2 MiB scratch

    void* args[] = {
        (void*)&x, (void*)&W_ih0, (void*)&W_hh0, (void*)&b_ih0, (void*)&b_hh0,
        (void*)&W_ih1, (void*)&W_hh1, (void*)&b_ih1, (void*)&b_hh1,
        (void*)&xp, (void*)&out
    };
    hipLaunchCooperativeKernel((const void*)fused_rnn, dim3(GRID), dim3(BLK),
                               args, 0, stream);
}

// Round 3
// 45.435 us; speedup vs baseline: 1.5212x; 1.5212x over previous
//
#include <hip/hip_runtime.h>
#include <math.h>

#define S_LEN 2048
#define B_SZ  256
#define I_SZ  128
#define GRID  256
#define BLK   256

// exact identity: tanh(x) = 1 - 2/(1 + e^{2x}); saturates correctly at +/-inf
__device__ __forceinline__ float fast_tanh(float x) {
    float e = __expf(2.0f * x);                       // v_exp_f32
    return 1.0f - 2.0f * __builtin_amdgcn_rcpf(e + 1.0f);
}

// Single ordinary launch, three phases, no grid-wide barrier:
//  phase 0 (every thread, O(K)): truncation window from the actual recurrent
//    weights. Starting (h1,h2)=(0,0) at t0=S-K gives |dh2_last| <= (1+K)*m^K
//    (tanh 1-Lipschitz, |true h| <= 1); sigmoid Lipschitz 1/4 =>
//    out err <= (1+K)m^K/4. Require (1+K)m^K <= 4e-3 => err <= 1e-3 (thr 8.5e-3).
//  phase 1: xp[s*B+b] = dot(x[s,b,:], W_ih0) + bias for s >= t0. One wave = 2
//    vectors/iter, float4/lane (64*16B = 1KiB coalesced), shfl_xor reduce.
//  phase 2: LAST-ARRIVING block (ticket atomic) runs the 256-lane scan.
//    Safe vs dispatch order: no block ever waits on a non-resident block.
//    Cross-XCD: release __threadfence before the ticket add (L2 writeback),
//    acquire fence after winning it (L2 invalidate) before reading xp.
__global__ __launch_bounds__(BLK) void fused_rnn(
    const float* __restrict__ x,
    const float* __restrict__ W_ih0,
    const float* __restrict__ w_hh0,
    const float* __restrict__ b_ih0,
    const float* __restrict__ b_hh0,
    const float* __restrict__ w_ih1,
    const float* __restrict__ w_hh1,
    const float* __restrict__ b_ih1,
    const float* __restrict__ b_hh1,
    float* __restrict__ xp,
    unsigned* __restrict__ ticket,
    float* __restrict__ out)
{
    // ---- phase 0: window ----
    const float m = fmaxf(fabsf(w_hh0[0]), fabsf(w_hh1[0]));
    int K = S_LEN;
    float p = 1.0f;
    for (int k = 1; k < S_LEN; ++k) {
        p *= m;
        if (p * (1.0f + (float)k) <= 4.0e-3f) { K = k; break; }
    }
    const int t0 = S_LEN - K;

    // ---- phase 1: matvec for rows >= t0 ----
    {
        const int lane = threadIdx.x & 63;
        const int half = lane >> 5;
        const int l    = lane & 31;
        const int wave  = (blockIdx.x * BLK + threadIdx.x) >> 6;
        const int nwave = (GRID * BLK) >> 6;

        const float4 w4  = ((const float4*)W_ih0)[l];
        const float bias = b_ih0[0] + b_hh0[0];

        const int P         = (S_LEN * B_SZ) / 2;
        const int startPair = t0 * (B_SZ / 2);

        for (int pr = startPair + wave; pr < P; pr += nwave) {
            const int v = 2 * pr + half;               // vector index = s*B + b
            float4 a = ((const float4*)x)[v * (I_SZ / 4) + l];
            float s = a.x * w4.x + a.y * w4.y + a.z * w4.z + a.w * w4.w;
            s += __shfl_xor(s, 1);
            s += __shfl_xor(s, 2);
            s += __shfl_xor(s, 4);
            s += __shfl_xor(s, 8);
            s += __shfl_xor(s, 16);
            if (l == 0) xp[v] = s + bias;
        }
    }

    // ---- ticket: last block to arrive does the scan ----
    __threadfence();                      // release xp writes (L2 writeback)
    __shared__ int is_last;
    if (threadIdx.x == 0) {
        unsigned old = __hip_atomic_fetch_add(ticket, 1u, __ATOMIC_ACQ_REL,
                                              __HIP_MEMORY_SCOPE_AGENT);
        is_last = (old == (unsigned)(GRID - 1));
    }
    __syncthreads();
    if (!is_last) return;
    __threadfence();                      // acquire before reading others' xp

    // ---- phase 2: scan, one lane per batch element ----
    const int b   = threadIdx.x;
    const float w0 = w_hh0[0];
    const float c  = w_ih1[0];
    const float d  = w_hh1[0];
    const float b1 = b_ih1[0] + b_hh1[0];

    float h1 = 0.0f, h2 = 0.0f;
    float nxt = xp[t0 * B_SZ + b];
    for (int t = t0; t < S_LEN; ++t) {
        float cur = nxt;
        if (t + 1 < S_LEN) nxt = xp[(t + 1) * B_SZ + b];
        h1 = fast_tanh(fmaf(w0, h1, cur));
        h2 = fast_tanh(fmaf(d, h2, fmaf(c, h1, b1)));
    }
    out[b] = __builtin_amdgcn_rcpf(1.0f + __expf(-h2));
}

extern "C" void kernel_launch(void* const* d_in, const int* in_sizes, int n_in,
                              void* d_out, int out_size, void* d_ws, size_t ws_size,
                              hipStream_t stream) {
    const float* x     = (const float*)d_in[0];
    const float* W_ih0 = (const float*)d_in[1];
    const float* W_hh0 = (const float*)d_in[2];
    const float* b_ih0 = (const float*)d_in[3];
    const float* b_hh0 = (const float*)d_in[4];
    const float* W_ih1 = (const float*)d_in[5];
    const float* W_hh1 = (const float*)d_in[6];
    const float* b_ih1 = (const float*)d_in[7];
    const float* b_hh1 = (const float*)d_in[8];
    float* out = (float*)d_out;

    unsigned* ticket = (unsigned*)d_ws;                  // 4 B, zeroed each call
    float*    xp     = (float*)((char*)d_ws + 256);      // S*B floats = 2 MiB

    hipMemsetAsync(ticket, 0, sizeof(unsigned), stream); // graph memset node
    fused_rnn<<<GRID, BLK, 0, stream>>>(x, W_ih0, W_hh0, b_ih0, b_hh0,
                                        W_ih1, W_hh1, b_ih1, b_hh1,
                                        xp, ticket, out);
}

// Round 4
// 15.355 us; speedup vs baseline: 4.5014x; 2.9591x over previous
//
#include <hip/hip_runtime.h>
#include <math.h>

#define S_LEN 2048
#define B_SZ  256
#define I_SZ  128
#define BLK   256

// exact identity: tanh(x) = 1 - 2/(1 + e^{2x}); saturates correctly at +/-inf
__device__ __forceinline__ float fast_tanh(float x) {
    float e = __expf(2.0f * x);                       // v_exp_f32
    return 1.0f - 2.0f * __builtin_amdgcn_rcpf(e + 1.0f);
}

// One block per batch element; zero cross-block communication.
// Error analysis (m = max(|w_hh0|,|w_hh1|) < 1, tanh 1-Lipschitz, |h|<=1):
//   each h1[t] sub-scan starts h=0 at t-K  -> |dh1[t]| <= m^K
//   h2 chain starts h2=0 at t0=S-K        -> |dh2_last| <= m^K + K*|c|*m^K
//                                          <= (1+K) m^K
//   sigmoid Lipschitz 1/4 => out err <= (1+K)m^K / 4.
// K chosen smallest with (1+K)m^K <= 4e-3  => out err <= 1e-3 (thr 8.5e-3).
// If m ~ 1 this degenerates to the exact full scan (slow but correct).
__global__ __launch_bounds__(BLK) void rnn_block(
    const float* __restrict__ x,
    const float* __restrict__ W_ih0,
    const float* __restrict__ w_hh0,
    const float* __restrict__ b_ih0,
    const float* __restrict__ b_hh0,
    const float* __restrict__ w_ih1,
    const float* __restrict__ w_hh1,
    const float* __restrict__ b_ih1,
    const float* __restrict__ b_hh1,
    float* __restrict__ out)
{
    // ---- phase 0: window (every thread, O(K) scalar) ----
    const float wr = w_hh0[0];
    const float m  = fmaxf(fabsf(wr), fabsf(w_hh1[0]));
    int K = S_LEN;
    float p = 1.0f;
    for (int k = 1; k < S_LEN; ++k) {
        p *= m;
        if (p * (1.0f + (float)k) <= 4.0e-3f) { K = k; break; }
    }
    const int t0    = S_LEN - K;                      // h2 chain start
    const int w0row = (t0 >= K) ? (t0 - K) : 0;       // first projected row
    const int R     = S_LEN - w0row;                  // rows of xp needed (<= 2K)

    __shared__ float xp[S_LEN];    // xp[i] = proj of row w0row+i   (<= 8 KB)
    __shared__ float h1s[S_LEN];   // h1s[i] = h1 at t0+i           (<= 8 KB)

    const int b = blockIdx.x;

    // ---- phase 1: xp column for this batch element ----
    // 8 groups of 32 lanes; each group does one row: 32 x float4 = 512 B
    // coalesced, 5-step shfl_xor reduce within the 32-lane half-wave.
    {
        const int grp = threadIdx.x >> 5;
        const int l   = threadIdx.x & 31;
        const float4 w4   = ((const float4*)W_ih0)[l];
        const float bias0 = b_ih0[0] + b_hh0[0];
        for (int i = grp; i < R; i += BLK / 32) {
            const size_t row = (size_t)(w0row + i) * B_SZ + b;
            float4 a = ((const float4*)(x + row * I_SZ))[l];
            float s = a.x * w4.x + a.y * w4.y + a.z * w4.z + a.w * w4.w;
            s += __shfl_xor(s, 1);
            s += __shfl_xor(s, 2);
            s += __shfl_xor(s, 4);
            s += __shfl_xor(s, 8);
            s += __shfl_xor(s, 16);
            if (l == 0) xp[i] = s + bias0;
        }
    }
    __syncthreads();

    // ---- phase 2: parallel truncated h1 sub-scans (one thread per t) ----
    for (int i = threadIdx.x; i < K; i += BLK) {
        const int t  = t0 + i;
        int s0 = t - K; if (s0 < w0row) s0 = w0row;   // ==0 case is exact
        float h = 0.0f;
        for (int tau = s0; tau <= t; ++tau)
            h = fast_tanh(fmaf(wr, h, xp[tau - w0row]));
        h1s[i] = h;
    }
    __syncthreads();

    // ---- phase 3: serial h2 chain + sigmoid (thread 0) ----
    if (threadIdx.x == 0) {
        const float c  = w_ih1[0];
        const float d  = w_hh1[0];
        const float b1 = b_ih1[0] + b_hh1[0];
        float h2 = 0.0f;
        for (int i = 0; i < K; ++i)
            h2 = fast_tanh(fmaf(d, h2, fmaf(c, h1s[i], b1)));
        out[b] = __builtin_amdgcn_rcpf(1.0f + __expf(-h2));
    }
}

extern "C" void kernel_launch(void* const* d_in, const int* in_sizes, int n_in,
                              void* d_out, int out_size, void* d_ws, size_t ws_size,
                              hipStream_t stream) {
    const float* x     = (const float*)d_in[0];
    const float* W_ih0 = (const float*)d_in[1];
    const float* W_hh0 = (const float*)d_in[2];
    const float* b_ih0 = (const float*)d_in[3];
    const float* b_hh0 = (const float*)d_in[4];
    const float* W_ih1 = (const float*)d_in[5];
    const float* W_hh1 = (const float*)d_in[6];
    const float* b_ih1 = (const float*)d_in[7];
    const float* b_hh1 = (const float*)d_in[8];
    float* out = (float*)d_out;

    rnn_block<<<B_SZ, BLK, 0, stream>>>(x, W_ih0, W_hh0, b_ih0, b_hh0,
                                        W_ih1, W_hh1, b_ih1, b_hh1, out);
}

// Round 5
// 12.450 us; speedup vs baseline: 5.5516x; 1.2333x over previous
//
#include <hip/hip_runtime.h>
#include <math.h>

#define S_LEN 2048
#define B_SZ  256
#define I_SZ  128
#define BLK   256

#define LOG2E  1.4426950408889634f

// One block per batch element; zero cross-block communication; one dispatch.
//
// Error analysis (m = max(|w_hh0|,|w_hh1|) < 1, tanh 1-Lipschitz, |h|<=1):
//   each h1[t] sub-scan starts h=0 at t-K  -> |dh1[t]| <= m^K
//   h2 chain starts h2=0 at t0=S-K         -> |dh2_last| <= (1+K) m^K
//   sigmoid Lipschitz 1/4                  -> out err <= (1+K) m^K / 4
// K = smallest with (1+K)m^K <= 4e-3  =>  out err <= 1e-3 (threshold 8.5e-3).
// If m ~ 1 this degenerates to the exact full scan (slow but correct).
//
// Numerics: work in g = 2h domain with exp args pre-scaled by log2(e):
//   tanh step: A = wrl*g + xq[t]          (wrl = w*log2e, xq = 2*log2e*(proj+b))
//              g' = 2 - 4/(2^A + 1)        == 2*tanh(w*g/2 + proj + b)
// Dependent chain per step: fmaf -> v_exp -> add -> rcp -> fmaf (all native).
__global__ __launch_bounds__(BLK) void rnn_block(
    const float* __restrict__ x,
    const float* __restrict__ W_ih0,
    const float* __restrict__ w_hh0,
    const float* __restrict__ b_ih0,
    const float* __restrict__ b_hh0,
    const float* __restrict__ w_ih1,
    const float* __restrict__ w_hh1,
    const float* __restrict__ b_ih1,
    const float* __restrict__ b_hh1,
    float* __restrict__ out)
{
    // ---- phase 0: truncation window, closed form + verify ----
    const float wr = w_hh0[0];
    const float m  = fmaxf(fabsf(wr), fabsf(w_hh1[0]));
    int K;
    if (m >= 0.999f) {
        K = S_LEN;                               // near-critical: exact scan
    } else if (m <= 1.0e-6f) {
        K = 1;
    } else {
        const float lm = log2f(m);               // < 0
        const float tgt = log2f(4.0e-3f);
        float Kf = 16.0f;
        #pragma unroll
        for (int it = 0; it < 3; ++it)
            Kf = (tgt - log2f(1.0f + Kf)) / lm;  // fixed point of the bound
        K = (int)ceilf(Kf);
        if (K < 1) K = 1;
        if (K > S_LEN) K = S_LEN;
        // rigorous: bump K until (1+K)*m^K <= 4e-3 (or full scan)
        while (K < S_LEN &&
               (1.0f + (float)K) * __builtin_amdgcn_exp2f((float)K * lm) > 4.0e-3f)
            ++K;
    }
    const int t0    = S_LEN - K;                 // h2 chain start
    const int w0row = (t0 >= K) ? (t0 - K) : 0;  // first projected row
    const int R     = S_LEN - w0row;             // rows of xq needed (<= 2K)

    __shared__ float xq[S_LEN];   // 2*log2e*(proj + bias0) per row
    __shared__ float u[S_LEN];    // log2e*(2*c*h1 + 2*b1) per scan step

    const int b = blockIdx.x;

    // ---- phase 1: projected column, 8 groups x 32 lanes, 2 rows in flight ----
    {
        const int grp = threadIdx.x >> 5;
        const int l   = threadIdx.x & 31;
        float4 w4 = ((const float4*)W_ih0)[l];
        const float sc = 2.0f * LOG2E;
        w4.x *= sc; w4.y *= sc; w4.z *= sc; w4.w *= sc;
        const float bias = sc * (b_ih0[0] + b_hh0[0]);
        const float* xb = x + ((size_t)w0row * B_SZ + b) * I_SZ;
        const size_t rowstride = (size_t)B_SZ * I_SZ;

        int i = grp;
        for (; i + 8 < R; i += 16) {             // rows i and i+8 concurrently
            float4 a0 = ((const float4*)(xb + (size_t)i * rowstride))[l];
            float4 a1 = ((const float4*)(xb + (size_t)(i + 8) * rowstride))[l];
            float s0 = a0.x*w4.x + a0.y*w4.y + a0.z*w4.z + a0.w*w4.w;
            float s1 = a1.x*w4.x + a1.y*w4.y + a1.z*w4.z + a1.w*w4.w;
            s0 += __shfl_xor(s0, 1);  s1 += __shfl_xor(s1, 1);
            s0 += __shfl_xor(s0, 2);  s1 += __shfl_xor(s1, 2);
            s0 += __shfl_xor(s0, 4);  s1 += __shfl_xor(s1, 4);
            s0 += __shfl_xor(s0, 8);  s1 += __shfl_xor(s1, 8);
            s0 += __shfl_xor(s0, 16); s1 += __shfl_xor(s1, 16);
            if (l == 0) { xq[i] = s0 + bias; xq[i + 8] = s1 + bias; }
        }
        for (; i < R; i += 8) {                  // remainder rows
            float4 a0 = ((const float4*)(xb + (size_t)i * rowstride))[l];
            float s0 = a0.x*w4.x + a0.y*w4.y + a0.z*w4.z + a0.w*w4.w;
            s0 += __shfl_xor(s0, 1);
            s0 += __shfl_xor(s0, 2);
            s0 += __shfl_xor(s0, 4);
            s0 += __shfl_xor(s0, 8);
            s0 += __shfl_xor(s0, 16);
            if (l == 0) xq[i] = s0 + bias;
        }
    }
    __syncthreads();

    // ---- phase 2: parallel truncated h1 sub-scans (one thread per t) ----
    const float wrl = wr * LOG2E;
    const float cl  = w_ih1[0] * LOG2E;
    const float b1l = 2.0f * LOG2E * (b_ih1[0] + b_hh1[0]);
    for (int i = threadIdx.x; i < K; i += BLK) {
        const int t  = t0 + i;
        int s0 = t - K; if (s0 < w0row) s0 = w0row;   // ==0 case is exact
        float g = 0.0f;
        for (int tau = s0; tau <= t; ++tau) {
            float A = fmaf(wrl, g, xq[tau - w0row]);
            float e = __builtin_amdgcn_exp2f(A);
            g = fmaf(-4.0f, __builtin_amdgcn_rcpf(e + 1.0f), 2.0f);
        }
        u[i] = fmaf(cl, g, b1l);                 // layer-1 input term, pre-folded
    }
    __syncthreads();

    // ---- phase 3: serial h2 chain + sigmoid (thread 0) ----
    if (threadIdx.x == 0) {
        const float dl = w_hh1[0] * LOG2E;
        float g2 = 0.0f;
        for (int i = 0; i < K; ++i) {
            float A = fmaf(dl, g2, u[i]);
            float e = __builtin_amdgcn_exp2f(A);
            g2 = fmaf(-4.0f, __builtin_amdgcn_rcpf(e + 1.0f), 2.0f);
        }
        // sigmoid(h2) = 1/(1 + 2^(-g2*log2e/2))
        float e = __builtin_amdgcn_exp2f(-0.5f * LOG2E * g2);
        out[b] = __builtin_amdgcn_rcpf(1.0f + e);
    }
}

extern "C" void kernel_launch(void* const* d_in, const int* in_sizes, int n_in,
                              void* d_out, int out_size, void* d_ws, size_t ws_size,
                              hipStream_t stream) {
    const float* x     = (const float*)d_in[0];
    const float* W_ih0 = (const float*)d_in[1];
    const float* W_hh0 = (const float*)d_in[2];
    const float* b_ih0 = (const float*)d_in[3];
    const float* b_hh0 = (const float*)d_in[4];
    const float* W_ih1 = (const float*)d_in[5];
    const float* W_hh1 = (const float*)d_in[6];
    const float* b_ih1 = (const float*)d_in[7];
    const float* b_hh1 = (const float*)d_in[8];
    float* out = (float*)d_out;

    rnn_block<<<B_SZ, BLK, 0, stream>>>(x, W_ih0, W_hh0, b_ih0, b_hh0,
                                        W_ih1, W_hh1, b_ih1, b_hh1, out);
}

// Round 6
// 12.083 us; speedup vs baseline: 5.7202x; 1.0304x over previous
//
#include <hip/hip_runtime.h>
#include <math.h>

#define S_LEN 2048
#define B_SZ  256
#define I_SZ  128
#define BLK   256

#define LOG2E  1.4426950408889634f

// smallest K in [1, S_LEN] with a^K <= tol  (a = |weight| < 1), closed form
// + rigorous verify-bump (bound is enforced exactly, closed form is a guess).
__device__ __forceinline__ int window_len(float a, float tol) {
    if (a >= 0.9995f) return S_LEN;          // near-critical: exact full scan
    if (a <= 1.0e-6f) return 1;
    const float la = log2f(a);               // < 0
    int K = (int)ceilf(log2f(tol) / la);
    if (K < 1) K = 1;
    if (K > S_LEN) K = S_LEN;
    while (K < S_LEN && __builtin_amdgcn_exp2f((float)K * la) > tol) ++K;
    return K;
}

// One block per batch element; zero cross-block communication; one dispatch.
//
// Split-window error analysis (tanh 1-Lipschitz, |h|<=1, |c|=|w_ih1|<=1):
//   h1 sub-scans, start 0 at t-K1:  |dh1[t]| <= |wr|^K1 =: e1
//   h2 chain, start 0 at t0=S-K2:   |dh2| <= |d|^K2 + e1*sum_j |d|^j
//                                         <= |d|^K2 + e1*min(K2, 1/(1-|d|))
//   K2: |d|^K2 <= 2e-3;  K1: |wr|^K1 <= 2e-3/amp, amp=min(K2,1/(1-|d|))
//   sigmoid Lipschitz 1/4  =>  out err <= (2e-3+2e-3)/4 = 1e-3  (thr 8.5e-3).
// Degenerates to the exact full scan when |wr| or |d| -> 1 (slow but correct).
//
// Numerics: g = 2h domain, exp args pre-scaled by log2(e):
//   A = wrl*g + xq[t];  g' = 2 - 4/(2^A + 1)  == 2*tanh(wr*g/2 + proj + bias)
// Dependent chain per step: fmaf -> v_exp -> add -> rcp -> fmaf (all native).
__global__ __launch_bounds__(BLK) void rnn_block(
    const float* __restrict__ x,
    const float* __restrict__ W_ih0,
    const float* __restrict__ w_hh0,
    const float* __restrict__ b_ih0,
    const float* __restrict__ b_hh0,
    const float* __restrict__ w_ih1,
    const float* __restrict__ w_hh1,
    const float* __restrict__ b_ih1,
    const float* __restrict__ b_hh1,
    float* __restrict__ out)
{
    // ---- phase 0: split truncation windows ----
    const float wr = w_hh0[0];
    const float d  = w_hh1[0];
    const float aw = fabsf(wr);
    const float ad = fabsf(d);

    const int K2 = window_len(ad, 2.0e-3f);
    const float amp = fminf((float)K2, 1.0f / (1.0f - ad));  // ad==1 -> inf -> K2
    const int K1 = window_len(aw, 2.0e-3f / amp);

    const int t0    = S_LEN - K2;                // h2 chain start
    int w0 = t0 - K1; if (w0 < 0) w0 = 0;        // first projected row
    const int R = S_LEN - w0;                    // rows needed (= K1+K2 clamped)

    __shared__ float xq[S_LEN];   // 2*log2e*(proj + bias0) per row
    __shared__ float u[S_LEN];    // log2e*(2*c*h1 + 2*b1) per h2 step

    const int b = blockIdx.x;

    // ---- phase 1: projected column; 8 groups x 32 lanes, 4 rows in flight
    //      per group (32 rows / block) to cover HBM latency ----
    {
        const int grp = threadIdx.x >> 5;
        const int l   = threadIdx.x & 31;
        float4 w4 = ((const float4*)W_ih0)[l];
        const float sc = 2.0f * LOG2E;
        w4.x *= sc; w4.y *= sc; w4.z *= sc; w4.w *= sc;
        const float bias = sc * (b_ih0[0] + b_hh0[0]);
        const float* xb = x + ((size_t)w0 * B_SZ + b) * I_SZ;
        const size_t rs = (size_t)B_SZ * I_SZ;   // row stride in floats

        int i = grp;
        for (; i + 24 < R; i += 32) {            // rows i, i+8, i+16, i+24
            const float* p0 = xb + (size_t)i * rs;
            float4 a0 = ((const float4*)(p0          ))[l];
            float4 a1 = ((const float4*)(p0 +  8 * rs))[l];
            float4 a2 = ((const float4*)(p0 + 16 * rs))[l];
            float4 a3 = ((const float4*)(p0 + 24 * rs))[l];
            float s0 = a0.x*w4.x + a0.y*w4.y + a0.z*w4.z + a0.w*w4.w;
            float s1 = a1.x*w4.x + a1.y*w4.y + a1.z*w4.z + a1.w*w4.w;
            float s2 = a2.x*w4.x + a2.y*w4.y + a2.z*w4.z + a2.w*w4.w;
            float s3 = a3.x*w4.x + a3.y*w4.y + a3.z*w4.z + a3.w*w4.w;
            #pragma unroll
            for (int sh = 1; sh <= 16; sh <<= 1) {
                s0 += __shfl_xor(s0, sh);
                s1 += __shfl_xor(s1, sh);
                s2 += __shfl_xor(s2, sh);
                s3 += __shfl_xor(s3, sh);
            }
            if (l == 0) {
                xq[i]      = s0 + bias;
                xq[i +  8] = s1 + bias;
                xq[i + 16] = s2 + bias;
                xq[i + 24] = s3 + bias;
            }
        }
        for (; i < R; i += 8) {                  // remainder rows
            float4 a0 = ((const float4*)(xb + (size_t)i * rs))[l];
            float s0 = a0.x*w4.x + a0.y*w4.y + a0.z*w4.z + a0.w*w4.w;
            #pragma unroll
            for (int sh = 1; sh <= 16; sh <<= 1) s0 += __shfl_xor(s0, sh);
            if (l == 0) xq[i] = s0 + bias;
        }
    }
    __syncthreads();

    // ---- phase 2: parallel truncated h1 sub-scans (one thread per t) ----
    const float wrl = wr * LOG2E;
    const float cl  = w_ih1[0] * LOG2E;
    const float b1l = 2.0f * LOG2E * (b_ih1[0] + b_hh1[0]);
    for (int i = threadIdx.x; i < K2; i += BLK) {
        const int t  = t0 + i;
        int s0 = t - K1; if (s0 < 0) s0 = 0;     // ==0 case is exact
        float g = 0.0f;
        for (int tau = s0; tau <= t; ++tau) {
            float A = fmaf(wrl, g, xq[tau - w0]);
            float e = __builtin_amdgcn_exp2f(A);
            g = fmaf(-4.0f, __builtin_amdgcn_rcpf(e + 1.0f), 2.0f);
        }
        u[i] = fmaf(cl, g, b1l);                 // layer-1 input term, pre-folded
    }
    __syncthreads();

    // ---- phase 3: serial h2 chain + sigmoid (thread 0) ----
    if (threadIdx.x == 0) {
        const float dl = d * LOG2E;
        float g2 = 0.0f;
        for (int i = 0; i < K2; ++i) {
            float A = fmaf(dl, g2, u[i]);
            float e = __builtin_amdgcn_exp2f(A);
            g2 = fmaf(-4.0f, __builtin_amdgcn_rcpf(e + 1.0f), 2.0f);
        }
        // sigmoid(h2) = 1/(1 + 2^(-g2*log2e/2))
        float e = __builtin_amdgcn_exp2f(-0.5f * LOG2E * g2);
        out[b] = __builtin_amdgcn_rcpf(1.0f + e);
    }
}

extern "C" void kernel_launch(void* const* d_in, const int* in_sizes, int n_in,
                              void* d_out, int out_size, void* d_ws, size_t ws_size,
                              hipStream_t stream) {
    const float* x     = (const float*)d_in[0];
    const float* W_ih0 = (const float*)d_in[1];
    const float* W_hh0 = (const float*)d_in[2];
    const float* b_ih0 = (const float*)d_in[3];
    const float* b_hh0 = (const float*)d_in[4];
    const float* W_ih1 = (const float*)d_in[5];
    const float* W_hh1 = (const float*)d_in[6];
    const float* b_ih1 = (const float*)d_in[7];
    const float* b_hh1 = (const float*)d_in[8];
    float* out = (float*)d_out;

    rnn_block<<<B_SZ, BLK, 0, stream>>>(x, W_ih0, W_hh0, b_ih0, b_hh0,
                                        W_ih1, W_hh1, b_ih1, b_hh1, out);
}